// Round 14
// baseline (251.431 us; speedup 1.0000x reference)
//
#include <hip/hip_runtime.h>

typedef __attribute__((ext_vector_type(8))) short short8;
typedef __attribute__((ext_vector_type(4))) float f32x4;

#define S_LEN 2048
#define DH 64

__device__ __forceinline__ unsigned short f2bf(float x) {
  unsigned u = __builtin_bit_cast(unsigned, x);
  u += 0x7fffu + ((u >> 16) & 1u);
  return (unsigned short)(u >> 16);
}

// ---- detect whether mask was passed as uint8 (stride 1) or int32 (stride 4)
__global__ void detect_stride_k(const unsigned char* __restrict__ m, int* flag) {
  __shared__ int any;
  if (threadIdx.x == 0) any = 0;
  __syncthreads();
  int acc = 0;
  for (int i = threadIdx.x; i < 4096; i += 256)
    if (i & 3) acc |= m[i];
  if (acc) atomicOr(&any, 1);
  __syncthreads();
  if (threadIdx.x == 0) *flag = any ? 1 : 4;
}

// ---- merged prep: conv K->bf16 | transpose V->bf16 | pack mask bits ----
__global__ void prep_kernel(const float* __restrict__ k,
                            const float* __restrict__ v,
                            const unsigned char* __restrict__ m,
                            const int* __restrict__ flagp,
                            char* __restrict__ kbf,
                            char* __restrict__ vtbf,
                            unsigned* __restrict__ bits) {
  int bid = blockIdx.x;
  if (bid < 2048) {
    int idx = bid * 256 + threadIdx.x;
    const float4* s = (const float4*)k + (size_t)idx * 2;
    float4 a = s[0], b = s[1];
    int4 o;
    o.x = (int)f2bf(a.x) | ((int)f2bf(a.y) << 16);
    o.y = (int)f2bf(a.z) | ((int)f2bf(a.w) << 16);
    o.z = (int)f2bf(b.x) | ((int)f2bf(b.y) << 16);
    o.w = (int)f2bf(b.z) | ((int)f2bf(b.w) << 16);
    ((int4*)kbf)[idx] = o;
  } else if (bid < 6144) {
    int gt = (bid - 2048) * 256 + threadIdx.x;
    int wid = gt >> 6;
    int lane = gt & 63;
    int bh = wid >> 9;
    int rem = wid & 511;
    int d0 = (rem >> 5) * 4;
    int t = (rem & 31) * 64 + lane;
    float4 val = *(const float4*)(v + ((size_t)bh * S_LEN + t) * DH + d0);
    unsigned short* o = (unsigned short*)vtbf;
    size_t base = ((size_t)bh * DH + d0) * S_LEN + t;
    o[base]             = f2bf(val.x);
    o[base + S_LEN]     = f2bf(val.y);
    o[base + 2 * S_LEN] = f2bf(val.z);
    o[base + 3 * S_LEN] = f2bf(val.w);
  } else {
    int idx = (bid - 6144) * 256 + threadIdx.x;
    unsigned wword = 0;
    if (*flagp == 1) {
      const uint4* p = (const uint4*)(m + (size_t)idx * 32);
      uint4 a = p[0], bq = p[1];
      unsigned arr[8] = {a.x, a.y, a.z, a.w, bq.x, bq.y, bq.z, bq.w};
#pragma unroll
      for (int d = 0; d < 8; ++d)
#pragma unroll
        for (int j = 0; j < 4; ++j)
          wword |= (((arr[d] >> (8 * j)) & 255u) != 0u ? 1u : 0u) << (d * 4 + j);
    } else {
      const uint4* p = (const uint4*)m + (size_t)idx * 8;
#pragma unroll
      for (int d = 0; d < 8; ++d) {
        uint4 vv = p[d];
        wword |= (vv.x ? 1u : 0u) << (d * 4);
        wword |= (vv.y ? 1u : 0u) << (d * 4 + 1);
        wword |= (vv.z ? 1u : 0u) << (d * 4 + 2);
        wword |= (vv.w ? 1u : 0u) << (d * 4 + 3);
      }
    }
    bits[idx] = wword;
  }
}

// ======= FUSED (R9 structure): pass A staged dbuf; pass B staged dbuf with
// counted-vmcnt barrier; nt stores. 512 blocks x 8 waves (16 q-rows each). =====
__global__ __launch_bounds__(512, 4)
void attn_fused(const float* __restrict__ qsrc,
                const unsigned* __restrict__ mbits,
                const char* __restrict__ kbf,
                const char* __restrict__ vtbf,
                float* __restrict__ out) {
  // 80 KiB: kbuf[2][16K] | vbuf[2][16K] | pbuf[16K]
  __shared__ __align__(16) char smem[81920];

  const int tid = threadIdx.x;
  const int lane = tid & 63;
  const int w = tid >> 6;              // 0..7
  const int l15 = lane & 15;
  const int g = lane >> 4;
  const int sw = (l15 & 7) << 4;

  // XCD-aware swizzle: 512 blocks -> 4 consecutive bh per XCD
  int raw = blockIdx.x;
  int swz = (raw & 7) * 64 + (raw >> 3);
  const int bh = swz >> 4;
  const int qblk = swz & 15;
  const int b = bh >> 4;
  const int q0 = qblk * 128 + w * 16;  // this wave's 16 q-rows

  const char* ksrc_bh = kbf + (size_t)bh * (S_LEN * DH * 2);
  const char* vsrc_bh = vtbf + (size_t)bh * (DH * S_LEN * 2);
  char* pb = smem + 65536 + w * 2048;  // 16 rows x 128 B, wave-private

  // this lane's q-row bitmask pointer: 64 words per row
  const unsigned* mrow = mbits + (size_t)b * (S_LEN * (S_LEN / 32)) +
                         (size_t)(q0 + l15) * (S_LEN / 32);

  auto stageK = [&](int buf, int t0) {
    char* dst = smem + buf * 16384;
#pragma unroll
    for (int it = 0; it < 2; ++it) {
      int o = (w * 2 + it) * 1024 + lane * 16;
      int r = o >> 7;
      int inner = o & 127;
      const char* gp = ksrc_bh + (size_t)t0 * 128 + r * 128 + (inner ^ ((r & 7) << 4));
      __builtin_amdgcn_global_load_lds((const unsigned*)gp,
                                       (unsigned*)(dst + (w * 2 + it) * 1024), 16, 0, 0);
    }
  };
  auto stageV = [&](int buf, int t0) {
    char* dst = smem + 32768 + buf * 16384;
#pragma unroll
    for (int it = 0; it < 2; ++it) {
      int o = (w * 2 + it) * 1024 + lane * 16;
      int r = o >> 8;
      int inner = o & 255;
      const char* gp = vsrc_bh + (size_t)t0 * 2 + (size_t)r * (S_LEN * 2) +
                       (inner ^ ((r & 7) << 4));
      __builtin_amdgcn_global_load_lds((const unsigned*)gp,
                                       (unsigned*)(dst + (w * 2 + it) * 1024), 16, 0, 0);
    }
  };

  // Q fragments (B operand of swapped QK^T): lane holds Q[q0+l15][32kc+8g+j]
  short8 qf[2];
#pragma unroll
  for (int kc = 0; kc < 2; ++kc) {
    const float* qp = qsrc + ((size_t)bh * S_LEN + q0 + l15) * DH + 32 * kc + 8 * g;
    float4 x = *(const float4*)qp;
    float4 y = *(const float4*)(qp + 4);
    short8 f;
    f[0] = (short)f2bf(x.x); f[1] = (short)f2bf(x.y);
    f[2] = (short)f2bf(x.z); f[3] = (short)f2bf(x.w);
    f[4] = (short)f2bf(y.x); f[5] = (short)f2bf(y.y);
    f[6] = (short)f2bf(y.z); f[7] = (short)f2bf(y.w);
    qf[kc] = f;
  }

  f32x4 acc[4];
#pragma unroll
  for (int i = 0; i < 4; ++i) acc[i] = (f32x4){0.f, 0.f, 0.f, 0.f};
  float lp = 0.f;

  // ---------------- PASS A (pipelined, staged) ----------------
  stageK(0, 0);
  stageV(0, 0);
  uint4 mw = *(const uint4*)mrow;      // tile-0 mask bits (128 t = 16 B)
  __syncthreads();
  int cur = 0;

  for (int t0 = 0; t0 < S_LEN; t0 += 128) {
    uint4 mw_n;
    if (t0 + 128 < S_LEN) {            // async prefetch of next tile
      stageK(cur ^ 1, t0 + 128);
      stageV(cur ^ 1, t0 + 128);
      mw_n = *(const uint4*)(mrow + (t0 + 128) / 32);
    }
    const char* kbuf = smem + cur * 16384;
    const char* vbuf = smem + 32768 + cur * 16384;

    // GEMM1 (swapped): lane holds S[q=q0+l15][t=t0+16tc+4g+r]
    f32x4 sf[8];
#pragma unroll
    for (int tc = 0; tc < 8; ++tc) {
      const char* rowp = kbuf + (16 * tc + l15) * 128;
      short8 a0 = *(const short8*)(rowp + ((16 * g) ^ sw));
      short8 a1 = *(const short8*)(rowp + ((64 + 16 * g) ^ sw));
      f32x4 z = (f32x4){0.f, 0.f, 0.f, 0.f};
      f32x4 t00 = __builtin_amdgcn_mfma_f32_16x16x32_bf16(a0, qf[0], z, 0, 0, 0);
      sf[tc] = __builtin_amdgcn_mfma_f32_16x16x32_bf16(a1, qf[1], t00, 0, 0, 0);
    }

    // two 64-t halves: mask+exp+pack P -> GEMM2 (wave-private pbuf, no barrier)
    const unsigned mwa[4] = {mw.x, mw.y, mw.z, mw.w};
#pragma unroll
    for (int h = 0; h < 2; ++h) {
      char* pbr = pb + l15 * 128;
#pragma unroll
      for (int tq = 0; tq < 4; ++tq) {
        const int tc = 4 * h + tq;
        unsigned nib = (mwa[tc >> 1] >> (16 * (tc & 1) + 4 * g)) & 15u;
        float s0 = (nib & 1u) ? -1e9f : sf[tc][0] * 0.125f;
        float s1 = (nib & 2u) ? -1e9f : sf[tc][1] * 0.125f;
        float s2 = (nib & 4u) ? -1e9f : sf[tc][2] * 0.125f;
        float s3 = (nib & 8u) ? -1e9f : sf[tc][3] * 0.125f;
        lp += __expf(s0) + __expf(s1) + __expf(s2) + __expf(s3);
        int2 pk;
        asm("v_cvt_pk_bf16_f32 %0, %1, %2" : "=v"(pk.x) : "v"(s0), "v"(s1));
        asm("v_cvt_pk_bf16_f32 %0, %1, %2" : "=v"(pk.y) : "v"(s2), "v"(s3));
        *(int2*)(pbr + ((32 * tq + 8 * g) ^ sw)) = pk;
      }
      short8 p0 = *(const short8*)(pb + l15 * 128 + ((16 * g) ^ sw));
      short8 p1 = *(const short8*)(pb + l15 * 128 + ((64 + 16 * g) ^ sw));
#pragma unroll
      for (int dr = 0; dr < 4; ++dr) {
        const char* vr = vbuf + (16 * dr + l15) * 256;
        short8 v0 = *(const short8*)(vr + ((h * 128 + 16 * g) ^ sw));
        short8 v1 = *(const short8*)(vr + ((h * 128 + 64 + 16 * g) ^ sw));
        acc[dr] = __builtin_amdgcn_mfma_f32_16x16x32_bf16(v0, p0, acc[dr], 0, 0, 0);
        acc[dr] = __builtin_amdgcn_mfma_f32_16x16x32_bf16(v1, p1, acc[dr], 0, 0, 0);
      }
    }

    mw = mw_n;
    __syncthreads();   // drains prefetch (covered by compute) + guards buffers
    cur ^= 1;
  }

  // row sums (row q0+l15 lives on lanes {l15, +16, +32, +48})
  float l = lp;
  l += __shfl_xor(l, 16);
  l += __shfl_xor(l, 32);
  const float inv = 1.0f / l;

  // write results: acc^T C-layout -> out[bh][q][d], float4 along d (nt)
#pragma unroll
  for (int dr = 0; dr < 4; ++dr) {
    __builtin_nontemporal_store(acc[dr],
        (f32x4*)(out + ((size_t)bh * S_LEN + q0 + l15) * DH + 16 * dr + 4 * g));
  }

  // ---------------- PASS B (staged K dbuf, counted-vmcnt barrier) ----------
  float* att = out + (size_t)4194304 + (size_t)bh * S_LEN * S_LEN;
  stageK(0, 0);
  mw = *(const uint4*)mrow;
  __syncthreads();
  cur = 0;

  const int q = q0 + l15;
  for (int t0 = 0; t0 < S_LEN; t0 += 128) {
    uint4 mw_n;
    if (t0 + 128 < S_LEN) {
      stageK(cur ^ 1, t0 + 128);     // 2 global_load_lds (oldest vmem ops)
      mw_n = *(const uint4*)(mrow + (t0 + 128) / 32);
    }
    const char* kbuf = smem + cur * 16384;
    const unsigned mwa[4] = {mw.x, mw.y, mw.z, mw.w};

#pragma unroll
    for (int tc = 0; tc < 8; ++tc) {
      const char* rowp = kbuf + (16 * tc + l15) * 128;
      short8 a0 = *(const short8*)(rowp + ((16 * g) ^ sw));
      short8 a1 = *(const short8*)(rowp + ((64 + 16 * g) ^ sw));
      f32x4 z = (f32x4){0.f, 0.f, 0.f, 0.f};
      f32x4 t0f = __builtin_amdgcn_mfma_f32_16x16x32_bf16(a0, qf[0], z, 0, 0, 0);
      f32x4 sff = __builtin_amdgcn_mfma_f32_16x16x32_bf16(a1, qf[1], t0f, 0, 0, 0);
      const int t = t0 + 16 * tc + 4 * g;
      unsigned nib = (mwa[tc >> 1] >> (16 * (tc & 1) + 4 * g)) & 15u;
      float s0 = (nib & 1u) ? -1e9f : sff[0] * 0.125f;
      float s1 = (nib & 2u) ? -1e9f : sff[1] * 0.125f;
      float s2 = (nib & 4u) ? -1e9f : sff[2] * 0.125f;
      float s3 = (nib & 8u) ? -1e9f : sff[3] * 0.125f;
      f32x4 e;
      e[0] = __expf(s0) * inv;
      e[1] = __expf(s1) * inv;
      e[2] = __expf(s2) * inv;
      e[3] = __expf(s3) * inv;
      __builtin_nontemporal_store(e, (f32x4*)(att + (size_t)q * S_LEN + t));
    }

    mw = mw_n;
    // counted barrier: the 8 newest vmem ops (this tile's nt stores) may stay
    // in flight; anything older — the 2 staging loads — is provably retired.
    asm volatile("s_waitcnt vmcnt(8)" ::: "memory");
    __builtin_amdgcn_s_barrier();
    cur ^= 1;
  }
}

extern "C" void kernel_launch(void* const* d_in, const int* in_sizes, int n_in,
                              void* d_out, int out_size, void* d_ws, size_t ws_size,
                              hipStream_t stream) {
  (void)in_sizes; (void)n_in; (void)out_size; (void)ws_size;
  const float* q = (const float*)d_in[0];
  const float* k = (const float*)d_in[1];
  const float* v = (const float*)d_in[2];
  const unsigned char* mask = (const unsigned char*)d_in[3];
  float* out = (float*)d_out;

  char* ws = (char*)d_ws;
  int* flag = (int*)ws;
  char* kbf = ws + 256;                           // 8 MiB bf16 K
  char* vtbf = ws + 256 + 8 * 1024 * 1024;        // 8 MiB bf16 V^T
  unsigned* bits = (unsigned*)(ws + 256 + 16 * 1024 * 1024);  // 1 MiB bitmask

  detect_stride_k<<<1, 256, 0, stream>>>(mask, flag);
  prep_kernel<<<7168, 256, 0, stream>>>(k, v, mask, flag, kbf, vtbf, bits);
  attn_fused<<<512, 512, 0, stream>>>(q, bits, kbf, vtbf, out);
}

// Round 15
// 218.619 us; speedup vs baseline: 1.1501x; 1.1501x over previous
//
#include <hip/hip_runtime.h>

typedef __attribute__((ext_vector_type(8))) short short8;
typedef __attribute__((ext_vector_type(4))) float f32x4;

#define S_LEN 2048
#define DH 64

__device__ __forceinline__ unsigned short f2bf(float x) {
  unsigned u = __builtin_bit_cast(unsigned, x);
  u += 0x7fffu + ((u >> 16) & 1u);
  return (unsigned short)(u >> 16);
}

// ---- detect whether mask was passed as uint8 (stride 1) or int32 (stride 4)
__global__ void detect_stride_k(const unsigned char* __restrict__ m, int* flag) {
  __shared__ int any;
  if (threadIdx.x == 0) any = 0;
  __syncthreads();
  int acc = 0;
  for (int i = threadIdx.x; i < 4096; i += 256)
    if (i & 3) acc |= m[i];
  if (acc) atomicOr(&any, 1);
  __syncthreads();
  if (threadIdx.x == 0) *flag = any ? 1 : 4;
}

// ---- merged prep: conv K->bf16 | transpose V->bf16 | pack mask bits ----
__global__ void prep_kernel(const float* __restrict__ k,
                            const float* __restrict__ v,
                            const unsigned char* __restrict__ m,
                            const int* __restrict__ flagp,
                            char* __restrict__ kbf,
                            char* __restrict__ vtbf,
                            unsigned* __restrict__ bits) {
  int bid = blockIdx.x;
  if (bid < 2048) {
    int idx = bid * 256 + threadIdx.x;
    const float4* s = (const float4*)k + (size_t)idx * 2;
    float4 a = s[0], b = s[1];
    int4 o;
    o.x = (int)f2bf(a.x) | ((int)f2bf(a.y) << 16);
    o.y = (int)f2bf(a.z) | ((int)f2bf(a.w) << 16);
    o.z = (int)f2bf(b.x) | ((int)f2bf(b.y) << 16);
    o.w = (int)f2bf(b.z) | ((int)f2bf(b.w) << 16);
    ((int4*)kbf)[idx] = o;
  } else if (bid < 6144) {
    int gt = (bid - 2048) * 256 + threadIdx.x;
    int wid = gt >> 6;
    int lane = gt & 63;
    int bh = wid >> 9;
    int rem = wid & 511;
    int d0 = (rem >> 5) * 4;
    int t = (rem & 31) * 64 + lane;
    float4 val = *(const float4*)(v + ((size_t)bh * S_LEN + t) * DH + d0);
    unsigned short* o = (unsigned short*)vtbf;
    size_t base = ((size_t)bh * DH + d0) * S_LEN + t;
    o[base]             = f2bf(val.x);
    o[base + S_LEN]     = f2bf(val.y);
    o[base + 2 * S_LEN] = f2bf(val.z);
    o[base + 3 * S_LEN] = f2bf(val.w);
  } else {
    int idx = (bid - 6144) * 256 + threadIdx.x;
    unsigned wword = 0;
    if (*flagp == 1) {
      const uint4* p = (const uint4*)(m + (size_t)idx * 32);
      uint4 a = p[0], bq = p[1];
      unsigned arr[8] = {a.x, a.y, a.z, a.w, bq.x, bq.y, bq.z, bq.w};
#pragma unroll
      for (int d = 0; d < 8; ++d)
#pragma unroll
        for (int j = 0; j < 4; ++j)
          wword |= (((arr[d] >> (8 * j)) & 255u) != 0u ? 1u : 0u) << (d * 4 + j);
    } else {
      const uint4* p = (const uint4*)m + (size_t)idx * 8;
#pragma unroll
      for (int d = 0; d < 8; ++d) {
        uint4 vv = p[d];
        wword |= (vv.x ? 1u : 0u) << (d * 4);
        wword |= (vv.y ? 1u : 0u) << (d * 4 + 1);
        wword |= (vv.z ? 1u : 0u) << (d * 4 + 2);
        wword |= (vv.w ? 1u : 0u) << (d * 4 + 3);
      }
    }
    bits[idx] = wword;
  }
}

// ======= FUSED (R9): pass A staged dbuf; pass B staged dbuf with counted
// vmcnt barrier. 512 blocks x 8 waves (16 q-rows each). =====================
__global__ __launch_bounds__(512, 4)
void attn_fused(const float* __restrict__ qsrc,
                const unsigned* __restrict__ mbits,
                const char* __restrict__ kbf,
                const char* __restrict__ vtbf,
                float* __restrict__ out) {
  // 80 KiB: kbuf[2][16K] | vbuf[2][16K] | pbuf[16K]
  __shared__ __align__(16) char smem[81920];

  const int tid = threadIdx.x;
  const int lane = tid & 63;
  const int w = tid >> 6;              // 0..7
  const int l15 = lane & 15;
  const int g = lane >> 4;
  const int sw = (l15 & 7) << 4;

  // XCD-aware swizzle: 512 blocks -> 4 consecutive bh per XCD
  int raw = blockIdx.x;
  int swz = (raw & 7) * 64 + (raw >> 3);
  const int bh = swz >> 4;
  const int qblk = swz & 15;
  const int b = bh >> 4;
  const int q0 = qblk * 128 + w * 16;  // this wave's 16 q-rows

  const char* ksrc_bh = kbf + (size_t)bh * (S_LEN * DH * 2);
  const char* vsrc_bh = vtbf + (size_t)bh * (DH * S_LEN * 2);
  char* pb = smem + 65536 + w * 2048;  // 16 rows x 128 B, wave-private

  // this lane's q-row bitmask pointer: 64 words per row
  const unsigned* mrow = mbits + (size_t)b * (S_LEN * (S_LEN / 32)) +
                         (size_t)(q0 + l15) * (S_LEN / 32);

  auto stageK = [&](int buf, int t0) {
    char* dst = smem + buf * 16384;
#pragma unroll
    for (int it = 0; it < 2; ++it) {
      int o = (w * 2 + it) * 1024 + lane * 16;
      int r = o >> 7;
      int inner = o & 127;
      const char* gp = ksrc_bh + (size_t)t0 * 128 + r * 128 + (inner ^ ((r & 7) << 4));
      __builtin_amdgcn_global_load_lds((const unsigned*)gp,
                                       (unsigned*)(dst + (w * 2 + it) * 1024), 16, 0, 0);
    }
  };
  auto stageV = [&](int buf, int t0) {
    char* dst = smem + 32768 + buf * 16384;
#pragma unroll
    for (int it = 0; it < 2; ++it) {
      int o = (w * 2 + it) * 1024 + lane * 16;
      int r = o >> 8;
      int inner = o & 255;
      const char* gp = vsrc_bh + (size_t)t0 * 2 + (size_t)r * (S_LEN * 2) +
                       (inner ^ ((r & 7) << 4));
      __builtin_amdgcn_global_load_lds((const unsigned*)gp,
                                       (unsigned*)(dst + (w * 2 + it) * 1024), 16, 0, 0);
    }
  };

  // Q fragments (B operand of swapped QK^T): lane holds Q[q0+l15][32kc+8g+j]
  short8 qf[2];
#pragma unroll
  for (int kc = 0; kc < 2; ++kc) {
    const float* qp = qsrc + ((size_t)bh * S_LEN + q0 + l15) * DH + 32 * kc + 8 * g;
    float4 x = *(const float4*)qp;
    float4 y = *(const float4*)(qp + 4);
    short8 f;
    f[0] = (short)f2bf(x.x); f[1] = (short)f2bf(x.y);
    f[2] = (short)f2bf(x.z); f[3] = (short)f2bf(x.w);
    f[4] = (short)f2bf(y.x); f[5] = (short)f2bf(y.y);
    f[6] = (short)f2bf(y.z); f[7] = (short)f2bf(y.w);
    qf[kc] = f;
  }

  f32x4 acc[4];
#pragma unroll
  for (int i = 0; i < 4; ++i) acc[i] = (f32x4){0.f, 0.f, 0.f, 0.f};
  float lp = 0.f;

  // ---------------- PASS A (pipelined, staged) ----------------
  stageK(0, 0);
  stageV(0, 0);
  uint4 mw = *(const uint4*)mrow;      // tile-0 mask bits (128 t = 16 B)
  __syncthreads();
  int cur = 0;

  for (int t0 = 0; t0 < S_LEN; t0 += 128) {
    uint4 mw_n;
    if (t0 + 128 < S_LEN) {            // async prefetch of next tile
      stageK(cur ^ 1, t0 + 128);
      stageV(cur ^ 1, t0 + 128);
      mw_n = *(const uint4*)(mrow + (t0 + 128) / 32);
    }
    const char* kbuf = smem + cur * 16384;
    const char* vbuf = smem + 32768 + cur * 16384;

    // GEMM1 (swapped): lane holds S[q=q0+l15][t=t0+16tc+4g+r]
    f32x4 sf[8];
#pragma unroll
    for (int tc = 0; tc < 8; ++tc) {
      const char* rowp = kbuf + (16 * tc + l15) * 128;
      short8 a0 = *(const short8*)(rowp + ((16 * g) ^ sw));
      short8 a1 = *(const short8*)(rowp + ((64 + 16 * g) ^ sw));
      f32x4 z = (f32x4){0.f, 0.f, 0.f, 0.f};
      f32x4 t00 = __builtin_amdgcn_mfma_f32_16x16x32_bf16(a0, qf[0], z, 0, 0, 0);
      sf[tc] = __builtin_amdgcn_mfma_f32_16x16x32_bf16(a1, qf[1], t00, 0, 0, 0);
    }

    // two 64-t halves: mask+exp+pack P -> GEMM2 (wave-private pbuf, no barrier)
    const unsigned mwa[4] = {mw.x, mw.y, mw.z, mw.w};
#pragma unroll
    for (int h = 0; h < 2; ++h) {
      char* pbr = pb + l15 * 128;
#pragma unroll
      for (int tq = 0; tq < 4; ++tq) {
        const int tc = 4 * h + tq;
        unsigned nib = (mwa[tc >> 1] >> (16 * (tc & 1) + 4 * g)) & 15u;
        float s0 = (nib & 1u) ? -1e9f : sf[tc][0] * 0.125f;
        float s1 = (nib & 2u) ? -1e9f : sf[tc][1] * 0.125f;
        float s2 = (nib & 4u) ? -1e9f : sf[tc][2] * 0.125f;
        float s3 = (nib & 8u) ? -1e9f : sf[tc][3] * 0.125f;
        lp += __expf(s0) + __expf(s1) + __expf(s2) + __expf(s3);
        int2 pk;
        pk.x = (int)f2bf(s0) | ((int)f2bf(s1) << 16);
        pk.y = (int)f2bf(s2) | ((int)f2bf(s3) << 16);
        *(int2*)(pbr + ((32 * tq + 8 * g) ^ sw)) = pk;
      }
      short8 p0 = *(const short8*)(pb + l15 * 128 + ((16 * g) ^ sw));
      short8 p1 = *(const short8*)(pb + l15 * 128 + ((64 + 16 * g) ^ sw));
#pragma unroll
      for (int dr = 0; dr < 4; ++dr) {
        const char* vr = vbuf + (16 * dr + l15) * 256;
        short8 v0 = *(const short8*)(vr + ((h * 128 + 16 * g) ^ sw));
        short8 v1 = *(const short8*)(vr + ((h * 128 + 64 + 16 * g) ^ sw));
        acc[dr] = __builtin_amdgcn_mfma_f32_16x16x32_bf16(v0, p0, acc[dr], 0, 0, 0);
        acc[dr] = __builtin_amdgcn_mfma_f32_16x16x32_bf16(v1, p1, acc[dr], 0, 0, 0);
      }
    }

    mw = mw_n;
    __syncthreads();   // drains prefetch (covered by compute) + guards buffers
    cur ^= 1;
  }

  // row sums (row q0+l15 lives on lanes {l15, +16, +32, +48})
  float l = lp;
  l += __shfl_xor(l, 16);
  l += __shfl_xor(l, 32);
  const float inv = 1.0f / l;

  // write results: acc^T C-layout -> out[bh][q][d], float4 along d
#pragma unroll
  for (int dr = 0; dr < 4; ++dr) {
    float4 o;
    o.x = acc[dr][0]; o.y = acc[dr][1];
    o.z = acc[dr][2]; o.w = acc[dr][3];
    *(float4*)(out + ((size_t)bh * S_LEN + q0 + l15) * DH + 16 * dr + 4 * g) = o;
  }

  // ---------------- PASS B (staged K dbuf, counted-vmcnt barrier) ----------
  float* att = out + (size_t)4194304 + (size_t)bh * S_LEN * S_LEN;
  stageK(0, 0);
  mw = *(const uint4*)mrow;
  __syncthreads();
  cur = 0;

  const int q = q0 + l15;
  for (int t0 = 0; t0 < S_LEN; t0 += 128) {
    uint4 mw_n;
    if (t0 + 128 < S_LEN) {
      stageK(cur ^ 1, t0 + 128);     // 2 global_load_lds + 1 mask load (oldest)
      mw_n = *(const uint4*)(mrow + (t0 + 128) / 32);
    }
    const char* kbuf = smem + cur * 16384;
    const unsigned mwa[4] = {mw.x, mw.y, mw.z, mw.w};

#pragma unroll
    for (int tc = 0; tc < 8; ++tc) {
      const char* rowp = kbuf + (16 * tc + l15) * 128;
      short8 a0 = *(const short8*)(rowp + ((16 * g) ^ sw));
      short8 a1 = *(const short8*)(rowp + ((64 + 16 * g) ^ sw));
      f32x4 z = (f32x4){0.f, 0.f, 0.f, 0.f};
      f32x4 t0f = __builtin_amdgcn_mfma_f32_16x16x32_bf16(a0, qf[0], z, 0, 0, 0);
      f32x4 sff = __builtin_amdgcn_mfma_f32_16x16x32_bf16(a1, qf[1], t0f, 0, 0, 0);
      const int t = t0 + 16 * tc + 4 * g;
      unsigned nib = (mwa[tc >> 1] >> (16 * (tc & 1) + 4 * g)) & 15u;
      float s0 = (nib & 1u) ? -1e9f : sff[0] * 0.125f;
      float s1 = (nib & 2u) ? -1e9f : sff[1] * 0.125f;
      float s2 = (nib & 4u) ? -1e9f : sff[2] * 0.125f;
      float s3 = (nib & 8u) ? -1e9f : sff[3] * 0.125f;
      float4 e;
      e.x = __expf(s0) * inv;
      e.y = __expf(s1) * inv;
      e.z = __expf(s2) * inv;
      e.w = __expf(s3) * inv;
      *(float4*)(att + (size_t)q * S_LEN + t) = e;
    }

    mw = mw_n;
    // counted barrier (T4): the 8 newest vmem ops (this tile's stores) may
    // stay in flight; anything older — staging loads + mask load — retired.
    asm volatile("s_waitcnt vmcnt(8)" ::: "memory");
    __builtin_amdgcn_s_barrier();
    __builtin_amdgcn_sched_barrier(0);
    cur ^= 1;
  }
}

extern "C" void kernel_launch(void* const* d_in, const int* in_sizes, int n_in,
                              void* d_out, int out_size, void* d_ws, size_t ws_size,
                              hipStream_t stream) {
  (void)in_sizes; (void)n_in; (void)out_size; (void)ws_size;
  const float* q = (const float*)d_in[0];
  const float* k = (const float*)d_in[1];
  const float* v = (const float*)d_in[2];
  const unsigned char* mask = (const unsigned char*)d_in[3];
  float* out = (float*)d_out;

  char* ws = (char*)d_ws;
  int* flag = (int*)ws;
  char* kbf = ws + 256;                           // 8 MiB bf16 K
  char* vtbf = ws + 256 + 8 * 1024 * 1024;        // 8 MiB bf16 V^T
  unsigned* bits = (unsigned*)(ws + 256 + 16 * 1024 * 1024);  // 1 MiB bitmask

  detect_stride_k<<<1, 256, 0, stream>>>(mask, flag);
  prep_kernel<<<7168, 256, 0, stream>>>(k, v, mask, flag, kbf, vtbf, bits);
  attn_fused<<<512, 512, 0, stream>>>(q, bits, kbf, vtbf, out);
}

// Round 16
// 206.671 us; speedup vs baseline: 1.2166x; 1.0578x over previous
//
#include <hip/hip_runtime.h>

typedef __attribute__((ext_vector_type(8))) short short8;
typedef __attribute__((ext_vector_type(4))) float f32x4;

#define S_LEN 2048
#define DH 64

__device__ __forceinline__ unsigned short f2bf(float x) {
  unsigned u = __builtin_bit_cast(unsigned, x);
  u += 0x7fffu + ((u >> 16) & 1u);
  return (unsigned short)(u >> 16);
}

// ---- detect whether mask was passed as uint8 (stride 1) or int32 (stride 4)
__global__ void detect_stride_k(const unsigned char* __restrict__ m, int* flag) {
  __shared__ int any;
  if (threadIdx.x == 0) any = 0;
  __syncthreads();
  int acc = 0;
  for (int i = threadIdx.x; i < 4096; i += 256)
    if (i & 3) acc |= m[i];
  if (acc) atomicOr(&any, 1);
  __syncthreads();
  if (threadIdx.x == 0) *flag = any ? 1 : 4;
}

// ---- merged prep: conv K->bf16 | transpose V->bf16 | pack mask bits ----
__global__ void prep_kernel(const float* __restrict__ k,
                            const float* __restrict__ v,
                            const unsigned char* __restrict__ m,
                            const int* __restrict__ flagp,
                            char* __restrict__ kbf,
                            char* __restrict__ vtbf,
                            unsigned* __restrict__ bits) {
  int bid = blockIdx.x;
  if (bid < 2048) {
    int idx = bid * 256 + threadIdx.x;
    const float4* s = (const float4*)k + (size_t)idx * 2;
    float4 a = s[0], b = s[1];
    int4 o;
    o.x = (int)f2bf(a.x) | ((int)f2bf(a.y) << 16);
    o.y = (int)f2bf(a.z) | ((int)f2bf(a.w) << 16);
    o.z = (int)f2bf(b.x) | ((int)f2bf(b.y) << 16);
    o.w = (int)f2bf(b.z) | ((int)f2bf(b.w) << 16);
    ((int4*)kbf)[idx] = o;
  } else if (bid < 6144) {
    int gt = (bid - 2048) * 256 + threadIdx.x;
    int wid = gt >> 6;
    int lane = gt & 63;
    int bh = wid >> 9;
    int rem = wid & 511;
    int d0 = (rem >> 5) * 4;
    int t = (rem & 31) * 64 + lane;
    float4 val = *(const float4*)(v + ((size_t)bh * S_LEN + t) * DH + d0);
    unsigned short* o = (unsigned short*)vtbf;
    size_t base = ((size_t)bh * DH + d0) * S_LEN + t;
    o[base]             = f2bf(val.x);
    o[base + S_LEN]     = f2bf(val.y);
    o[base + 2 * S_LEN] = f2bf(val.z);
    o[base + 3 * S_LEN] = f2bf(val.w);
  } else {
    int idx = (bid - 6144) * 256 + threadIdx.x;
    unsigned wword = 0;
    if (*flagp == 1) {
      const uint4* p = (const uint4*)(m + (size_t)idx * 32);
      uint4 a = p[0], bq = p[1];
      unsigned arr[8] = {a.x, a.y, a.z, a.w, bq.x, bq.y, bq.z, bq.w};
#pragma unroll
      for (int d = 0; d < 8; ++d)
#pragma unroll
        for (int j = 0; j < 4; ++j)
          wword |= (((arr[d] >> (8 * j)) & 255u) != 0u ? 1u : 0u) << (d * 4 + j);
    } else {
      const uint4* p = (const uint4*)m + (size_t)idx * 8;
#pragma unroll
      for (int d = 0; d < 8; ++d) {
        uint4 vv = p[d];
        wword |= (vv.x ? 1u : 0u) << (d * 4);
        wword |= (vv.y ? 1u : 0u) << (d * 4 + 1);
        wword |= (vv.z ? 1u : 0u) << (d * 4 + 2);
        wword |= (vv.w ? 1u : 0u) << (d * 4 + 3);
      }
    }
    bits[idx] = wword;
  }
}

// ======= FUSED (R9): pass A staged dbuf (swapped MFMA); pass B staged dbuf
// with NON-swapped MFMA -> quad-coalesced row-major stores. ==================
__global__ __launch_bounds__(512, 4)
void attn_fused(const float* __restrict__ qsrc,
                const unsigned* __restrict__ mbits,
                const char* __restrict__ kbf,
                const char* __restrict__ vtbf,
                float* __restrict__ out) {
  // 80 KiB: kbuf[2][16K] | vbuf[2][16K] | pbuf[16K]
  __shared__ __align__(16) char smem[81920];

  const int tid = threadIdx.x;
  const int lane = tid & 63;
  const int w = tid >> 6;              // 0..7
  const int l15 = lane & 15;
  const int g = lane >> 4;
  const int sw = (l15 & 7) << 4;

  // XCD-aware swizzle: 512 blocks -> 4 consecutive bh per XCD
  int raw = blockIdx.x;
  int swz = (raw & 7) * 64 + (raw >> 3);
  const int bh = swz >> 4;
  const int qblk = swz & 15;
  const int b = bh >> 4;
  const int q0 = qblk * 128 + w * 16;  // this wave's 16 q-rows

  const char* ksrc_bh = kbf + (size_t)bh * (S_LEN * DH * 2);
  const char* vsrc_bh = vtbf + (size_t)bh * (DH * S_LEN * 2);
  char* pb = smem + 65536 + w * 2048;  // 16 rows x 128 B, wave-private

  // this lane's q-row bitmask pointer: 64 words per row
  const unsigned* mrow = mbits + (size_t)b * (S_LEN * (S_LEN / 32)) +
                         (size_t)(q0 + l15) * (S_LEN / 32);

  auto stageK = [&](int buf, int t0) {
    char* dst = smem + buf * 16384;
#pragma unroll
    for (int it = 0; it < 2; ++it) {
      int o = (w * 2 + it) * 1024 + lane * 16;
      int r = o >> 7;
      int inner = o & 127;
      const char* gp = ksrc_bh + (size_t)t0 * 128 + r * 128 + (inner ^ ((r & 7) << 4));
      __builtin_amdgcn_global_load_lds((const unsigned*)gp,
                                       (unsigned*)(dst + (w * 2 + it) * 1024), 16, 0, 0);
    }
  };
  auto stageV = [&](int buf, int t0) {
    char* dst = smem + 32768 + buf * 16384;
#pragma unroll
    for (int it = 0; it < 2; ++it) {
      int o = (w * 2 + it) * 1024 + lane * 16;
      int r = o >> 8;
      int inner = o & 255;
      const char* gp = vsrc_bh + (size_t)t0 * 2 + (size_t)r * (S_LEN * 2) +
                       (inner ^ ((r & 7) << 4));
      __builtin_amdgcn_global_load_lds((const unsigned*)gp,
                                       (unsigned*)(dst + (w * 2 + it) * 1024), 16, 0, 0);
    }
  };

  // Q fragments: lane holds Q[q0+l15][32kc+8g+j]
  short8 qf[2];
#pragma unroll
  for (int kc = 0; kc < 2; ++kc) {
    const float* qp = qsrc + ((size_t)bh * S_LEN + q0 + l15) * DH + 32 * kc + 8 * g;
    float4 x = *(const float4*)qp;
    float4 y = *(const float4*)(qp + 4);
    short8 f;
    f[0] = (short)f2bf(x.x); f[1] = (short)f2bf(x.y);
    f[2] = (short)f2bf(x.z); f[3] = (short)f2bf(x.w);
    f[4] = (short)f2bf(y.x); f[5] = (short)f2bf(y.y);
    f[6] = (short)f2bf(y.z); f[7] = (short)f2bf(y.w);
    qf[kc] = f;
  }

  f32x4 acc[4];
#pragma unroll
  for (int i = 0; i < 4; ++i) acc[i] = (f32x4){0.f, 0.f, 0.f, 0.f};
  float lp = 0.f;

  // ---------------- PASS A (pipelined, staged; swapped MFMA) ----------------
  stageK(0, 0);
  stageV(0, 0);
  uint4 mw = *(const uint4*)mrow;      // tile-0 mask bits (128 t = 16 B)
  __syncthreads();
  int cur = 0;

  for (int t0 = 0; t0 < S_LEN; t0 += 128) {
    uint4 mw_n;
    if (t0 + 128 < S_LEN) {            // async prefetch of next tile
      stageK(cur ^ 1, t0 + 128);
      stageV(cur ^ 1, t0 + 128);
      mw_n = *(const uint4*)(mrow + (t0 + 128) / 32);
    }
    const char* kbuf = smem + cur * 16384;
    const char* vbuf = smem + 32768 + cur * 16384;

    // GEMM1 (swapped): lane holds S[q=q0+l15][t=t0+16tc+4g+r]
    f32x4 sf[8];
#pragma unroll
    for (int tc = 0; tc < 8; ++tc) {
      const char* rowp = kbuf + (16 * tc + l15) * 128;
      short8 a0 = *(const short8*)(rowp + ((16 * g) ^ sw));
      short8 a1 = *(const short8*)(rowp + ((64 + 16 * g) ^ sw));
      f32x4 z = (f32x4){0.f, 0.f, 0.f, 0.f};
      f32x4 t00 = __builtin_amdgcn_mfma_f32_16x16x32_bf16(a0, qf[0], z, 0, 0, 0);
      sf[tc] = __builtin_amdgcn_mfma_f32_16x16x32_bf16(a1, qf[1], t00, 0, 0, 0);
    }

    // two 64-t halves: mask+exp+pack P -> GEMM2 (wave-private pbuf, no barrier)
    const unsigned mwa[4] = {mw.x, mw.y, mw.z, mw.w};
#pragma unroll
    for (int h = 0; h < 2; ++h) {
      char* pbr = pb + l15 * 128;
#pragma unroll
      for (int tq = 0; tq < 4; ++tq) {
        const int tc = 4 * h + tq;
        unsigned nib = (mwa[tc >> 1] >> (16 * (tc & 1) + 4 * g)) & 15u;
        float s0 = (nib & 1u) ? -1e9f : sf[tc][0] * 0.125f;
        float s1 = (nib & 2u) ? -1e9f : sf[tc][1] * 0.125f;
        float s2 = (nib & 4u) ? -1e9f : sf[tc][2] * 0.125f;
        float s3 = (nib & 8u) ? -1e9f : sf[tc][3] * 0.125f;
        lp += __expf(s0) + __expf(s1) + __expf(s2) + __expf(s3);
        int2 pk;
        pk.x = (int)f2bf(s0) | ((int)f2bf(s1) << 16);
        pk.y = (int)f2bf(s2) | ((int)f2bf(s3) << 16);
        *(int2*)(pbr + ((32 * tq + 8 * g) ^ sw)) = pk;
      }
      short8 p0 = *(const short8*)(pb + l15 * 128 + ((16 * g) ^ sw));
      short8 p1 = *(const short8*)(pb + l15 * 128 + ((64 + 16 * g) ^ sw));
#pragma unroll
      for (int dr = 0; dr < 4; ++dr) {
        const char* vr = vbuf + (16 * dr + l15) * 256;
        short8 v0 = *(const short8*)(vr + ((h * 128 + 16 * g) ^ sw));
        short8 v1 = *(const short8*)(vr + ((h * 128 + 64 + 16 * g) ^ sw));
        acc[dr] = __builtin_amdgcn_mfma_f32_16x16x32_bf16(v0, p0, acc[dr], 0, 0, 0);
        acc[dr] = __builtin_amdgcn_mfma_f32_16x16x32_bf16(v1, p1, acc[dr], 0, 0, 0);
      }
    }

    mw = mw_n;
    __syncthreads();   // drains prefetch (covered by compute) + guards buffers
    cur ^= 1;
  }

  // row sums (row q0+l15 lives on lanes {l15, +16, +32, +48})
  float l = lp;
  l += __shfl_xor(l, 16);
  l += __shfl_xor(l, 32);
  const float inv = 1.0f / l;

  // write results: acc^T C-layout -> out[bh][q][d], float4 along d
#pragma unroll
  for (int dr = 0; dr < 4; ++dr) {
    float4 o;
    o.x = acc[dr][0]; o.y = acc[dr][1];
    o.z = acc[dr][2]; o.w = acc[dr][3];
    *(float4*)(out + ((size_t)bh * S_LEN + q0 + l15) * DH + 16 * dr + 4 * g) = o;
  }

  // ------- PASS B: non-swapped MFMA -> quad-coalesced row-major stores ------
  float* att = out + (size_t)4194304 + (size_t)bh * S_LEN * S_LEN;

  // inv for the 4 q-rows (q0+4g+r) this lane writes in the C row layout
  float invr[4];
#pragma unroll
  for (int r = 0; r < 4; ++r) invr[r] = __shfl(inv, 4 * g + r, 64);

  const unsigned* mrowB = mbits + (size_t)b * (S_LEN * (S_LEN / 32)) +
                          (size_t)(q0 + 4 * g) * (S_LEN / 32);

  stageK(0, 0);
  __syncthreads();
  cur = 0;

  for (int t0 = 0; t0 < S_LEN; t0 += 128) {
    if (t0 + 128 < S_LEN) stageK(cur ^ 1, t0 + 128);
    const char* kbuf = smem + cur * 16384;

    // mask words for this tile, one row per reg index r
    uint4 mv[4];
#pragma unroll
    for (int r = 0; r < 4; ++r) mv[r] = *(const uint4*)(mrowB + r * 64 + t0 / 32);

    float* attT = att + (size_t)(q0 + 4 * g) * S_LEN + t0 + l15;

#pragma unroll
    for (int tc = 0; tc < 8; ++tc) {
      const char* rowp = kbuf + (16 * tc + l15) * 128;
      short8 b0 = *(const short8*)(rowp + ((16 * g) ^ sw));
      short8 b1 = *(const short8*)(rowp + ((64 + 16 * g) ^ sw));
      f32x4 z = (f32x4){0.f, 0.f, 0.f, 0.f};
      // non-swapped: C[lane,reg r] = S[q0+4g+r][t0+16tc+l15]
      f32x4 t0f = __builtin_amdgcn_mfma_f32_16x16x32_bf16(qf[0], b0, z, 0, 0, 0);
      f32x4 sff = __builtin_amdgcn_mfma_f32_16x16x32_bf16(qf[1], b1, t0f, 0, 0, 0);
      const int bitsh = 16 * (tc & 1) + l15;
#pragma unroll
      for (int r = 0; r < 4; ++r) {
        unsigned word = (tc >> 1) == 0 ? mv[r].x : (tc >> 1) == 1 ? mv[r].y
                      : (tc >> 1) == 2 ? mv[r].z : mv[r].w;
        float s = ((word >> bitsh) & 1u) ? -1e9f : sff[r] * 0.125f;
        attT[(size_t)r * S_LEN + 16 * tc] = __expf(s) * invr[r];
      }
    }

    __syncthreads();
    cur ^= 1;
  }
}

extern "C" void kernel_launch(void* const* d_in, const int* in_sizes, int n_in,
                              void* d_out, int out_size, void* d_ws, size_t ws_size,
                              hipStream_t stream) {
  (void)in_sizes; (void)n_in; (void)out_size; (void)ws_size;
  const float* q = (const float*)d_in[0];
  const float* k = (const float*)d_in[1];
  const float* v = (const float*)d_in[2];
  const unsigned char* mask = (const unsigned char*)d_in[3];
  float* out = (float*)d_out;

  char* ws = (char*)d_ws;
  int* flag = (int*)ws;
  char* kbf = ws + 256;                           // 8 MiB bf16 K
  char* vtbf = ws + 256 + 8 * 1024 * 1024;        // 8 MiB bf16 V^T
  unsigned* bits = (unsigned*)(ws + 256 + 16 * 1024 * 1024);  // 1 MiB bitmask

  detect_stride_k<<<1, 256, 0, stream>>>(mask, flag);
  prep_kernel<<<7168, 256, 0, stream>>>(k, v, mask, flag, kbf, vtbf, bits);
  attn_fused<<<512, 512, 0, stream>>>(q, bits, kbf, vtbf, out);
}